// Round 9
// baseline (18010.822 us; speedup 1.0000x reference)
//
#include <hip/hip_runtime.h>

// BiLSTM(128->2x256) -> LayerNorm(512) -> BiLSTM(512->2x256), B=64 T=1024.
// f16 MFMA inputs, f32 accum/cell. Recurrence: 8 persistent WGs x 512 thr =
// (2 dir x 4 batch-group-of-16). Each WG holds the FULL recurrent matrix
// U(dir) in registers (8 waves x 256 VGPRs of B-frags = 512KB) and runs its
// group's entire U=256 recurrence ON ONE CU: h(t-1) in a 16KB LDS double
// buffer, sync = intra-CU s_barrier only. NO cross-WG communication, no
// sentinels, no polling, no device-coherent traffic. MFMA-throughput-bound:
// 512 MFMAs (16x16x32) per step per CU.

typedef __attribute__((ext_vector_type(8))) _Float16 half8;    // f16x8 MFMA frag
typedef __attribute__((ext_vector_type(4))) float f32x4;       // MFMA acc
typedef __attribute__((ext_vector_type(4))) unsigned short ushort4v;

#define LOG2E 1.4426950408889634f

static __device__ __forceinline__ unsigned short f2h(float f) {
  _Float16 h = (_Float16)f;
  return __builtin_bit_cast(unsigned short, h);
}
static __device__ __forceinline__ float h2f(unsigned short u) {
  _Float16 h = __builtin_bit_cast(_Float16, u);
  return (float)h;
}
static __device__ __forceinline__ float sigf(float x) {
  return __builtin_amdgcn_rcpf(1.f + __builtin_amdgcn_exp2f(-LOG2E * x));
}
static __device__ __forceinline__ float tanhf_(float x) {
  return 1.f - 2.f * __builtin_amdgcn_rcpf(__builtin_amdgcn_exp2f((2.f * LOG2E) * x) + 1.f);
}

// out[c][k] = f16(in[k][c]); in is [K][1024] f32, out is [1024][K] f16.
__global__ void k_transpose(const float* __restrict__ in, unsigned short* __restrict__ out, int K) {
  int idx = blockIdx.x * 256 + threadIdx.x;
  int c = idx / K, k = idx - c * K;
  out[idx] = f2h(in[k * 1024 + c]);
}

// x [b][t][128] f32 -> xb [(t*64+b)][128] f16
__global__ void k_cvtx(const float* __restrict__ x, unsigned short* __restrict__ xb) {
  int i = blockIdx.x * 256 + threadIdx.x;
  int o = i * 4;
  int k = o & 127, row = o >> 7;
  int b = row & 63, t = row >> 6;
  const f32x4 v = *(const f32x4*)(x + (size_t)((b << 10) + t) * 128 + k);
  ushort4v r;
  r.x = f2h(v.x); r.y = f2h(v.y); r.z = f2h(v.z); r.w = f2h(v.w);
  *(ushort4v*)(xb + o) = r;
}

// zx GEMM: A [65536 rows=(t*64+b)][K] f16 times Wt [1024][K] f16 (+bias)
// -> out [1024 t][1024 col][64 b] f16.  128x128 tiles, direct-global frags.
template<int K>
__global__ __launch_bounds__(256, 2) void k_zx(
    const unsigned short* __restrict__ A,
    const unsigned short* __restrict__ Wt_f, const unsigned short* __restrict__ Wt_b,
    const float* __restrict__ bias_f, const float* __restrict__ bias_b,
    unsigned short* __restrict__ out_f, unsigned short* __restrict__ out_b) {
  const int tid = threadIdx.x, w = tid >> 6, l = tid & 63;
  const int l16 = l & 15, lg = l >> 4;
  const int wm = w & 1, wn = w >> 1;
  const int rowbase = blockIdx.x * 128 + wm * 64;
  const int colbase = blockIdx.y * 128 + wn * 64;
  const unsigned short* Wt = blockIdx.z ? Wt_b : Wt_f;
  const float* bias = blockIdx.z ? bias_b : bias_f;
  unsigned short* out = blockIdx.z ? out_b : out_f;

  f32x4 acc[4][4];
#pragma unroll
  for (int nt = 0; nt < 4; nt++) {
    float bv = bias[colbase + nt * 16 + l16];
#pragma unroll
    for (int mt = 0; mt < 4; mt++) acc[mt][nt] = (f32x4){bv, bv, bv, bv};
  }

  for (int kf = 0; kf < K / 32; kf++) {
    const int ko = kf * 32 + lg * 8;
    half8 a[4], b[4];
#pragma unroll
    for (int mt = 0; mt < 4; mt++)
      a[mt] = *(const half8*)(A + (size_t)(rowbase + mt * 16 + l16) * K + ko);
#pragma unroll
    for (int nt = 0; nt < 4; nt++)
      b[nt] = *(const half8*)(Wt + (size_t)(colbase + nt * 16 + l16) * K + ko);
#pragma unroll
    for (int mt = 0; mt < 4; mt++)
#pragma unroll
      for (int nt = 0; nt < 4; nt++)
        acc[mt][nt] = __builtin_amdgcn_mfma_f32_16x16x32_f16(a[mt], b[nt], acc[mt][nt], 0, 0, 0);
  }

#pragma unroll
  for (int mt = 0; mt < 4; mt++) {
    const int rowchunk = rowbase + mt * 16;
    const int t = rowchunk >> 6;
    const int b0 = (rowchunk & 63) + lg * 4;
#pragma unroll
    for (int nt = 0; nt < 4; nt++) {
      const int c = colbase + nt * 16 + l16;
      ushort4v r;
      r.x = f2h(acc[mt][nt].x); r.y = f2h(acc[mt][nt].y);
      r.z = f2h(acc[mt][nt].z); r.w = f2h(acc[mt][nt].w);
      *(ushort4v*)(out + (((size_t)t << 10 | c) << 6) + b0) = r;
    }
  }
}

// Persistent recurrence, communication-free. 8 WGs x 512 thr: bid = d*4 + g.
// Wave wv owns u-range [wv*32, wv*32+32) across all 4 gates: B[q][ut][kf]
// resident in VGPRs (64 frags = 256 VGPRs). h(t-1) in LDS double buffer
// [slot][16 b][256 u] (XOR-swizzled). Per step per wave: 64 MFMAs.
template<int LAYER>
__global__ __launch_bounds__(512, 1) void k_rec5(
    const unsigned short* __restrict__ zx_f, const unsigned short* __restrict__ zx_b,
    const unsigned short* __restrict__ Ut_f, const unsigned short* __restrict__ Ut_b,
    unsigned short* __restrict__ h1,     // LAYER==1: [(tt*64+b)][512] f16
    float* __restrict__ out) {           // LAYER==2: [b][t][512] f32
  const int tid = threadIdx.x, wv = tid >> 6, l = tid & 63;
  const int l16 = l & 15, lg = l >> 4;
  const int bid = blockIdx.x;
  const int d = bid >> 2, g = bid & 3;
  const int b0 = g * 16;

  const unsigned short* zx = d ? zx_b : zx_f;
  const unsigned short* Ut = d ? Ut_b : Ut_f;

  __shared__ unsigned short hlds[2 * 16 * 256];   // 16KB double buffer

  // Resident U fragments: B[q][ut][kf]; lane l16 = output column u.
  half8 B[4][2][8];
#pragma unroll
  for (int q = 0; q < 4; q++)
#pragma unroll
    for (int ut = 0; ut < 2; ut++) {
      const int u = wv * 32 + ut * 16 + l16;
#pragma unroll
      for (int kf = 0; kf < 8; kf++)
        B[q][ut][kf] = *(const half8*)(Ut + (size_t)(q * 256 + u) * 256 + kf * 32 + lg * 8);
    }

  f32x4 c0 = (f32x4){0, 0, 0, 0}, c1 = (f32x4){0, 0, 0, 0};

  ushort4v zq[4][2];
  {
    const int t0 = d ? 1023 : 0;
#pragma unroll
    for (int q = 0; q < 4; q++)
#pragma unroll
      for (int ut = 0; ut < 2; ut++) {
        const int u = wv * 32 + ut * 16 + l16;
        zq[q][ut] = *(const ushort4v*)(zx + (((size_t)t0 << 10 | (q * 256 + u)) << 6) + b0 + lg * 4);
      }
  }

  for (int t = 0; t < 1024; t++) {
    const int tt = d ? 1023 - t : t;

    f32x4 acc[4][2];
#pragma unroll
    for (int q = 0; q < 4; q++)
#pragma unroll
      for (int ut = 0; ut < 2; ut++)
        acc[q][ut] = (f32x4){h2f(zq[q][ut].x), h2f(zq[q][ut].y),
                             h2f(zq[q][ut].z), h2f(zq[q][ut].w)};

    if (t > 0) {
      const int slot = ((t - 1) & 1) * 4096;
#pragma unroll
      for (int kf = 0; kf < 8; kf++) {
        // A-frag: row b = l16, K-slice = kf*32 + lg*8 over u_in (swizzled)
        const half8 ha = *(const half8*)&hlds[slot + ((l16 * 256 + kf * 32 + lg * 8) ^ ((l16 & 7) << 3))];
#pragma unroll
        for (int q = 0; q < 4; q++)
#pragma unroll
          for (int ut = 0; ut < 2; ut++)
            acc[q][ut] = __builtin_amdgcn_mfma_f32_16x16x32_f16(ha, B[q][ut][kf], acc[q][ut], 0, 0, 0);
      }
    }

    if (t + 1 < 1024) {   // prefetch next step's zx (hides under gates)
      const int tn = d ? tt - 1 : tt + 1;
#pragma unroll
      for (int q = 0; q < 4; q++)
#pragma unroll
        for (int ut = 0; ut < 2; ut++) {
          const int u = wv * 32 + ut * 16 + l16;
          zq[q][ut] = *(const ushort4v*)(zx + (((size_t)tn << 10 | (q * 256 + u)) << 6) + b0 + lg * 4);
        }
    }

    // gates; D-frag: row(b_local) = lg*4+rr, col(u) = l16
    const int wslot = (t & 1) * 4096;
#pragma unroll
    for (int ut = 0; ut < 2; ut++) {
      const int u = wv * 32 + ut * 16 + l16;
      f32x4& cc = ut ? c1 : c0;
#pragma unroll
      for (int rr = 0; rr < 4; rr++) {
        const float zi = acc[0][ut][rr], zf = acc[1][ut][rr];
        const float zg = acc[2][ut][rr], zo = acc[3][ut][rr];
        const float cn = sigf(zf) * cc[rr] + sigf(zi) * tanhf_(zg);
        cc[rr] = cn;
        const float hh = sigf(zo) * tanhf_(cn);
        const unsigned short hb = f2h(hh);
        const int bl = lg * 4 + rr;
        hlds[wslot + ((bl * 256 + u) ^ ((bl & 7) << 3))] = hb;
        if constexpr (LAYER == 1) {
          h1[(size_t)(tt * 64 + b0 + bl) * 512 + d * 256 + u] = hb;
        } else {
          out[((size_t)(b0 + bl) << 10 | tt) * 512 + d * 256 + u] = hh;
        }
      }
    }

    // intra-CU barrier: LDS writes visible to all 8 waves (no vmcnt drain)
    asm volatile("s_waitcnt lgkmcnt(0)" ::: "memory");
    __builtin_amdgcn_s_barrier();
  }
}

// LayerNorm over 512 features; one wave per row. f16 in/out, f32 math.
__global__ __launch_bounds__(256) void k_ln(
    const unsigned short* __restrict__ h1, const float* __restrict__ gamma,
    const float* __restrict__ beta, unsigned short* __restrict__ ln1) {
  const int tid = threadIdx.x, w = tid >> 6, l = tid & 63;
  const size_t row = (size_t)blockIdx.x * 4 + w;
  const unsigned short* src = h1 + row * 512 + l * 8;
  const ushort4v v0 = *(const ushort4v*)src;
  const ushort4v v1 = *(const ushort4v*)(src + 4);
  float xv[8] = {h2f(v0.x), h2f(v0.y), h2f(v0.z), h2f(v0.w),
                 h2f(v1.x), h2f(v1.y), h2f(v1.z), h2f(v1.w)};
  float sum = 0.f, ssq = 0.f;
#pragma unroll
  for (int i = 0; i < 8; i++) { sum += xv[i]; ssq += xv[i] * xv[i]; }
#pragma unroll
  for (int off = 32; off; off >>= 1) {
    sum += __shfl_xor(sum, off);
    ssq += __shfl_xor(ssq, off);
  }
  const float mu = sum * (1.f / 512.f);
  const float var = ssq * (1.f / 512.f) - mu * mu;
  const float rs = __builtin_amdgcn_rsqf(var + 1e-3f);
  const f32x4 g0 = *(const f32x4*)(gamma + l * 8);
  const f32x4 g1 = *(const f32x4*)(gamma + l * 8 + 4);
  const f32x4 e0 = *(const f32x4*)(beta + l * 8);
  const f32x4 e1 = *(const f32x4*)(beta + l * 8 + 4);
  float gg[8] = {g0.x, g0.y, g0.z, g0.w, g1.x, g1.y, g1.z, g1.w};
  float ee[8] = {e0.x, e0.y, e0.z, e0.w, e1.x, e1.y, e1.z, e1.w};
  unsigned short hh[8];
#pragma unroll
  for (int i = 0; i < 8; i++)
    hh[i] = f2h((xv[i] - mu) * rs * gg[i] + ee[i]);
  unsigned short* dst = ln1 + row * 512 + l * 8;
  *(ushort4v*)dst = (ushort4v){hh[0], hh[1], hh[2], hh[3]};
  *(ushort4v*)(dst + 4) = (ushort4v){hh[4], hh[5], hh[6], hh[7]};
}

extern "C" void kernel_launch(void* const* d_in, const int* in_sizes, int n_in,
                              void* d_out, int out_size, void* d_ws, size_t ws_size,
                              hipStream_t stream) {
  (void)in_sizes; (void)n_in; (void)out_size; (void)ws_size;
  const float* x     = (const float*)d_in[0];
  const float* W1f   = (const float*)d_in[1];
  const float* U1f   = (const float*)d_in[2];
  const float* b1f   = (const float*)d_in[3];
  const float* W1b   = (const float*)d_in[4];
  const float* U1b   = (const float*)d_in[5];
  const float* b1b   = (const float*)d_in[6];
  const float* gamma = (const float*)d_in[7];
  const float* beta  = (const float*)d_in[8];
  const float* W2f   = (const float*)d_in[9];
  const float* U2f   = (const float*)d_in[10];
  const float* b2f   = (const float*)d_in[11];
  const float* W2b   = (const float*)d_in[12];
  const float* U2b   = (const float*)d_in[13];
  const float* b2b   = (const float*)d_in[14];

  char* ws = (char*)d_ws;
  size_t ofs = 0;
  auto alloc = [&](size_t bytes) -> void* {
    void* p = ws + ofs;
    ofs += (bytes + 255) & ~(size_t)255;
    return p;
  };
  unsigned short* Wt1f  = (unsigned short*)alloc((size_t)1024*128*2);
  unsigned short* Wt1b  = (unsigned short*)alloc((size_t)1024*128*2);
  unsigned short* Ut1f  = (unsigned short*)alloc((size_t)1024*256*2);
  unsigned short* Ut1b  = (unsigned short*)alloc((size_t)1024*256*2);
  unsigned short* Ut2f  = (unsigned short*)alloc((size_t)1024*256*2);
  unsigned short* Ut2b  = (unsigned short*)alloc((size_t)1024*256*2);
  unsigned short* Wt2f  = (unsigned short*)alloc((size_t)1024*512*2);
  unsigned short* Wt2b  = (unsigned short*)alloc((size_t)1024*512*2);
  unsigned short* zxf   = (unsigned short*)alloc((size_t)1024*1024*64*2);  // 128MB
  unsigned short* zxb   = (unsigned short*)alloc((size_t)1024*1024*64*2);  // 128MB

  // d_out (128MB): xb [0,16MB) dead after zx1 -> h1 [0,64MB) output of
  // k_rec5<1>, dead after LN -> ln1 [64,128MB) dead after zx2 -> final f32
  // out overwrites all 128MB in k_rec5<2>.
  unsigned short* xb  = (unsigned short*)d_out;
  unsigned short* h1  = (unsigned short*)d_out;
  unsigned short* ln1 = (unsigned short*)d_out + (size_t)65536 * 512;

  k_transpose<<<1024 * 128 / 256, 256, 0, stream>>>(W1f, Wt1f, 128);
  k_transpose<<<1024 * 128 / 256, 256, 0, stream>>>(W1b, Wt1b, 128);
  k_transpose<<<1024 * 256 / 256, 256, 0, stream>>>(U1f, Ut1f, 256);
  k_transpose<<<1024 * 256 / 256, 256, 0, stream>>>(U1b, Ut1b, 256);
  k_transpose<<<1024 * 512 / 256, 256, 0, stream>>>(W2f, Wt2f, 512);
  k_transpose<<<1024 * 512 / 256, 256, 0, stream>>>(W2b, Wt2b, 512);
  k_transpose<<<1024 * 256 / 256, 256, 0, stream>>>(U2f, Ut2f, 256);
  k_transpose<<<1024 * 256 / 256, 256, 0, stream>>>(U2b, Ut2b, 256);
  k_cvtx<<<8192, 256, 0, stream>>>(x, xb);

  dim3 zgrid(512, 8, 2);
  k_zx<128><<<zgrid, 256, 0, stream>>>(xb, Wt1f, Wt1b, b1f, b1b, zxf, zxb);
  k_rec5<1><<<8, 512, 0, stream>>>(zxf, zxb, Ut1f, Ut1b, h1, nullptr);
  k_ln<<<65536 / 4, 256, 0, stream>>>(h1, gamma, beta, ln1);
  k_zx<512><<<zgrid, 256, 0, stream>>>(ln1, Wt2f, Wt2b, b2f, b2b, zxf, zxb);
  k_rec5<2><<<8, 512, 0, stream>>>(zxf, zxb, Ut2f, Ut2b, nullptr, (float*)d_out);
}

// Round 10
// 17687.549 us; speedup vs baseline: 1.0183x; 1.0183x over previous
//
#include <hip/hip_runtime.h>

// BiLSTM(128->2x256) -> LayerNorm(512) -> BiLSTM(512->2x256), B=64 T=1024.
// f16 MFMA inputs, f32 accum/cell. Recurrence: 8 persistent WGs x 1024 thr =
// (2 dir x 4 batch-group-of-16), 16 waves/WG. Each WG holds the FULL
// recurrent matrix U(dir) in registers (16 waves x 128 regs of B-frags =
// 512KB -> the per-wave footprint proven spill-free in rounds 5/6) and runs
// its group's entire U=256 recurrence ON ONE CU: h(t-1) in a 16KB LDS double
// buffer, sync = intra-CU s_barrier only. NO cross-WG communication.

typedef __attribute__((ext_vector_type(8))) _Float16 half8;    // f16x8 MFMA frag
typedef __attribute__((ext_vector_type(4))) float f32x4;       // MFMA acc
typedef __attribute__((ext_vector_type(4))) unsigned short ushort4v;

#define LOG2E 1.4426950408889634f

static __device__ __forceinline__ unsigned short f2h(float f) {
  _Float16 h = (_Float16)f;
  return __builtin_bit_cast(unsigned short, h);
}
static __device__ __forceinline__ float h2f(unsigned short u) {
  _Float16 h = __builtin_bit_cast(_Float16, u);
  return (float)h;
}
static __device__ __forceinline__ float sigf(float x) {
  return __builtin_amdgcn_rcpf(1.f + __builtin_amdgcn_exp2f(-LOG2E * x));
}
static __device__ __forceinline__ float tanhf_(float x) {
  return 1.f - 2.f * __builtin_amdgcn_rcpf(__builtin_amdgcn_exp2f((2.f * LOG2E) * x) + 1.f);
}

// out[c][k] = f16(in[k][c]); in is [K][1024] f32, out is [1024][K] f16.
__global__ void k_transpose(const float* __restrict__ in, unsigned short* __restrict__ out, int K) {
  int idx = blockIdx.x * 256 + threadIdx.x;
  int c = idx / K, k = idx - c * K;
  out[idx] = f2h(in[k * 1024 + c]);
}

// x [b][t][128] f32 -> xb [(t*64+b)][128] f16
__global__ void k_cvtx(const float* __restrict__ x, unsigned short* __restrict__ xb) {
  int i = blockIdx.x * 256 + threadIdx.x;
  int o = i * 4;
  int k = o & 127, row = o >> 7;
  int b = row & 63, t = row >> 6;
  const f32x4 v = *(const f32x4*)(x + (size_t)((b << 10) + t) * 128 + k);
  ushort4v r;
  r.x = f2h(v.x); r.y = f2h(v.y); r.z = f2h(v.z); r.w = f2h(v.w);
  *(ushort4v*)(xb + o) = r;
}

// zx GEMM: A [65536 rows=(t*64+b)][K] f16 times Wt [1024][K] f16 (+bias)
// -> out [1024 t][1024 col][64 b] f16.  128x128 tiles, direct-global frags.
template<int K>
__global__ __launch_bounds__(256, 2) void k_zx(
    const unsigned short* __restrict__ A,
    const unsigned short* __restrict__ Wt_f, const unsigned short* __restrict__ Wt_b,
    const float* __restrict__ bias_f, const float* __restrict__ bias_b,
    unsigned short* __restrict__ out_f, unsigned short* __restrict__ out_b) {
  const int tid = threadIdx.x, w = tid >> 6, l = tid & 63;
  const int l16 = l & 15, lg = l >> 4;
  const int wm = w & 1, wn = w >> 1;
  const int rowbase = blockIdx.x * 128 + wm * 64;
  const int colbase = blockIdx.y * 128 + wn * 64;
  const unsigned short* Wt = blockIdx.z ? Wt_b : Wt_f;
  const float* bias = blockIdx.z ? bias_b : bias_f;
  unsigned short* out = blockIdx.z ? out_b : out_f;

  f32x4 acc[4][4];
#pragma unroll
  for (int nt = 0; nt < 4; nt++) {
    float bv = bias[colbase + nt * 16 + l16];
#pragma unroll
    for (int mt = 0; mt < 4; mt++) acc[mt][nt] = (f32x4){bv, bv, bv, bv};
  }

  for (int kf = 0; kf < K / 32; kf++) {
    const int ko = kf * 32 + lg * 8;
    half8 a[4], b[4];
#pragma unroll
    for (int mt = 0; mt < 4; mt++)
      a[mt] = *(const half8*)(A + (size_t)(rowbase + mt * 16 + l16) * K + ko);
#pragma unroll
    for (int nt = 0; nt < 4; nt++)
      b[nt] = *(const half8*)(Wt + (size_t)(colbase + nt * 16 + l16) * K + ko);
#pragma unroll
    for (int mt = 0; mt < 4; mt++)
#pragma unroll
      for (int nt = 0; nt < 4; nt++)
        acc[mt][nt] = __builtin_amdgcn_mfma_f32_16x16x32_f16(a[mt], b[nt], acc[mt][nt], 0, 0, 0);
  }

#pragma unroll
  for (int mt = 0; mt < 4; mt++) {
    const int rowchunk = rowbase + mt * 16;
    const int t = rowchunk >> 6;
    const int b0 = (rowchunk & 63) + lg * 4;
#pragma unroll
    for (int nt = 0; nt < 4; nt++) {
      const int c = colbase + nt * 16 + l16;
      ushort4v r;
      r.x = f2h(acc[mt][nt].x); r.y = f2h(acc[mt][nt].y);
      r.z = f2h(acc[mt][nt].z); r.w = f2h(acc[mt][nt].w);
      *(ushort4v*)(out + (((size_t)t << 10 | c) << 6) + b0) = r;
    }
  }
}

// Persistent recurrence, communication-free. 8 WGs x 1024 thr: bid = d*4 + g.
// Wave wv (0..15) owns u-tile [wv*16, wv*16+16) across all 4 gates:
// B[q][kf] resident (32 frags = 128 regs/wave). h(t-1) in LDS double buffer
// [slot][16 b][256 u] (XOR-swizzled). Per step per wave: 32 MFMAs.
template<int LAYER>
__global__ __launch_bounds__(1024, 1) void k_rec6(
    const unsigned short* __restrict__ zx_f, const unsigned short* __restrict__ zx_b,
    const unsigned short* __restrict__ Ut_f, const unsigned short* __restrict__ Ut_b,
    unsigned short* __restrict__ h1,     // LAYER==1: [(tt*64+b)][512] f16
    float* __restrict__ out) {           // LAYER==2: [b][t][512] f32
  const int tid = threadIdx.x, wv = tid >> 6, l = tid & 63;
  const int l16 = l & 15, lg = l >> 4;
  const int bid = blockIdx.x;
  const int d = bid >> 2, g = bid & 3;
  const int b0 = g * 16;
  const int u = wv * 16 + l16;             // this lane's output u

  const unsigned short* zx = d ? zx_b : zx_f;
  const unsigned short* Ut = d ? Ut_b : Ut_f;

  __shared__ unsigned short hlds[2 * 16 * 256];   // 16KB double buffer

  // Resident U fragments: B[q][kf]; lane l16 = output column u.
  half8 B[4][8];
#pragma unroll
  for (int q = 0; q < 4; q++)
#pragma unroll
    for (int kf = 0; kf < 8; kf++)
      B[q][kf] = *(const half8*)(Ut + (size_t)(q * 256 + u) * 256 + kf * 32 + lg * 8);

  f32x4 c = (f32x4){0, 0, 0, 0};

  ushort4v zq[4];
  {
    const int t0 = d ? 1023 : 0;
#pragma unroll
    for (int q = 0; q < 4; q++)
      zq[q] = *(const ushort4v*)(zx + (((size_t)t0 << 10 | (q * 256 + u)) << 6) + b0 + lg * 4);
  }

  for (int t = 0; t < 1024; t++) {
    const int tt = d ? 1023 - t : t;

    f32x4 acc[4];
#pragma unroll
    for (int q = 0; q < 4; q++)
      acc[q] = (f32x4){h2f(zq[q].x), h2f(zq[q].y), h2f(zq[q].z), h2f(zq[q].w)};

    if (t > 0) {
      const int slot = ((t - 1) & 1) * 4096;
#pragma unroll
      for (int kf = 0; kf < 8; kf++) {
        // A-frag: row b = l16, K-slice = kf*32 + lg*8 over u_in (swizzled)
        const half8 ha = *(const half8*)&hlds[slot + ((l16 * 256 + kf * 32 + lg * 8) ^ ((l16 & 7) << 3))];
#pragma unroll
        for (int q = 0; q < 4; q++)
          acc[q] = __builtin_amdgcn_mfma_f32_16x16x32_f16(ha, B[q][kf], acc[q], 0, 0, 0);
      }
    }

    if (t + 1 < 1024) {   // prefetch next step's zx (hides under gates)
      const int tn = d ? tt - 1 : tt + 1;
#pragma unroll
      for (int q = 0; q < 4; q++)
        zq[q] = *(const ushort4v*)(zx + (((size_t)tn << 10 | (q * 256 + u)) << 6) + b0 + lg * 4);
    }

    // gates; D-frag: row(b_local) = lg*4+rr, col(u) = l16
    const int wslot = (t & 1) * 4096;
#pragma unroll
    for (int rr = 0; rr < 4; rr++) {
      const float zi = acc[0][rr], zf = acc[1][rr];
      const float zg = acc[2][rr], zo = acc[3][rr];
      const float cn = sigf(zf) * c[rr] + sigf(zi) * tanhf_(zg);
      c[rr] = cn;
      const float hh = sigf(zo) * tanhf_(cn);
      const unsigned short hb = f2h(hh);
      const int bl = lg * 4 + rr;
      hlds[wslot + ((bl * 256 + u) ^ ((bl & 7) << 3))] = hb;
      if constexpr (LAYER == 1) {
        h1[(size_t)(tt * 64 + b0 + bl) * 512 + d * 256 + u] = hb;
      } else {
        out[((size_t)(b0 + bl) << 10 | tt) * 512 + d * 256 + u] = hh;
      }
    }

    // intra-CU barrier: LDS writes visible to all 16 waves (no vmcnt drain)
    asm volatile("s_waitcnt lgkmcnt(0)" ::: "memory");
    __builtin_amdgcn_s_barrier();
  }
}

// LayerNorm over 512 features; one wave per row. f16 in/out, f32 math.
__global__ __launch_bounds__(256) void k_ln(
    const unsigned short* __restrict__ h1, const float* __restrict__ gamma,
    const float* __restrict__ beta, unsigned short* __restrict__ ln1) {
  const int tid = threadIdx.x, w = tid >> 6, l = tid & 63;
  const size_t row = (size_t)blockIdx.x * 4 + w;
  const unsigned short* src = h1 + row * 512 + l * 8;
  const ushort4v v0 = *(const ushort4v*)src;
  const ushort4v v1 = *(const ushort4v*)(src + 4);
  float xv[8] = {h2f(v0.x), h2f(v0.y), h2f(v0.z), h2f(v0.w),
                 h2f(v1.x), h2f(v1.y), h2f(v1.z), h2f(v1.w)};
  float sum = 0.f, ssq = 0.f;
#pragma unroll
  for (int i = 0; i < 8; i++) { sum += xv[i]; ssq += xv[i] * xv[i]; }
#pragma unroll
  for (int off = 32; off; off >>= 1) {
    sum += __shfl_xor(sum, off);
    ssq += __shfl_xor(ssq, off);
  }
  const float mu = sum * (1.f / 512.f);
  const float var = ssq * (1.f / 512.f) - mu * mu;
  const float rs = __builtin_amdgcn_rsqf(var + 1e-3f);
  const f32x4 g0 = *(const f32x4*)(gamma + l * 8);
  const f32x4 g1 = *(const f32x4*)(gamma + l * 8 + 4);
  const f32x4 e0 = *(const f32x4*)(beta + l * 8);
  const f32x4 e1 = *(const f32x4*)(beta + l * 8 + 4);
  float gg[8] = {g0.x, g0.y, g0.z, g0.w, g1.x, g1.y, g1.z, g1.w};
  float ee[8] = {e0.x, e0.y, e0.z, e0.w, e1.x, e1.y, e1.z, e1.w};
  unsigned short hh[8];
#pragma unroll
  for (int i = 0; i < 8; i++)
    hh[i] = f2h((xv[i] - mu) * rs * gg[i] + ee[i]);
  unsigned short* dst = ln1 + row * 512 + l * 8;
  *(ushort4v*)dst = (ushort4v){hh[0], hh[1], hh[2], hh[3]};
  *(ushort4v*)(dst + 4) = (ushort4v){hh[4], hh[5], hh[6], hh[7]};
}

extern "C" void kernel_launch(void* const* d_in, const int* in_sizes, int n_in,
                              void* d_out, int out_size, void* d_ws, size_t ws_size,
                              hipStream_t stream) {
  (void)in_sizes; (void)n_in; (void)out_size; (void)ws_size;
  const float* x     = (const float*)d_in[0];
  const float* W1f   = (const float*)d_in[1];
  const float* U1f   = (const float*)d_in[2];
  const float* b1f   = (const float*)d_in[3];
  const float* W1b   = (const float*)d_in[4];
  const float* U1b   = (const float*)d_in[5];
  const float* b1b   = (const float*)d_in[6];
  const float* gamma = (const float*)d_in[7];
  const float* beta  = (const float*)d_in[8];
  const float* W2f   = (const float*)d_in[9];
  const float* U2f   = (const float*)d_in[10];
  const float* b2f   = (const float*)d_in[11];
  const float* W2b   = (const float*)d_in[12];
  const float* U2b   = (const float*)d_in[13];
  const float* b2b   = (const float*)d_in[14];

  char* ws = (char*)d_ws;
  size_t ofs = 0;
  auto alloc = [&](size_t bytes) -> void* {
    void* p = ws + ofs;
    ofs += (bytes + 255) & ~(size_t)255;
    return p;
  };
  unsigned short* Wt1f  = (unsigned short*)alloc((size_t)1024*128*2);
  unsigned short* Wt1b  = (unsigned short*)alloc((size_t)1024*128*2);
  unsigned short* Ut1f  = (unsigned short*)alloc((size_t)1024*256*2);
  unsigned short* Ut1b  = (unsigned short*)alloc((size_t)1024*256*2);
  unsigned short* Ut2f  = (unsigned short*)alloc((size_t)1024*256*2);
  unsigned short* Ut2b  = (unsigned short*)alloc((size_t)1024*256*2);
  unsigned short* Wt2f  = (unsigned short*)alloc((size_t)1024*512*2);
  unsigned short* Wt2b  = (unsigned short*)alloc((size_t)1024*512*2);
  unsigned short* zxf   = (unsigned short*)alloc((size_t)1024*1024*64*2);  // 128MB
  unsigned short* zxb   = (unsigned short*)alloc((size_t)1024*1024*64*2);  // 128MB

  // d_out (128MB): xb [0,16MB) dead after zx1 -> h1 [0,64MB) output of
  // k_rec6<1>, dead after LN -> ln1 [64,128MB) dead after zx2 -> final f32
  // out overwrites all 128MB in k_rec6<2>.
  unsigned short* xb  = (unsigned short*)d_out;
  unsigned short* h1  = (unsigned short*)d_out;
  unsigned short* ln1 = (unsigned short*)d_out + (size_t)65536 * 512;

  k_transpose<<<1024 * 128 / 256, 256, 0, stream>>>(W1f, Wt1f, 128);
  k_transpose<<<1024 * 128 / 256, 256, 0, stream>>>(W1b, Wt1b, 128);
  k_transpose<<<1024 * 256 / 256, 256, 0, stream>>>(U1f, Ut1f, 256);
  k_transpose<<<1024 * 256 / 256, 256, 0, stream>>>(U1b, Ut1b, 256);
  k_transpose<<<1024 * 512 / 256, 256, 0, stream>>>(W2f, Wt2f, 512);
  k_transpose<<<1024 * 512 / 256, 256, 0, stream>>>(W2b, Wt2b, 512);
  k_transpose<<<1024 * 256 / 256, 256, 0, stream>>>(U2f, Ut2f, 256);
  k_transpose<<<1024 * 256 / 256, 256, 0, stream>>>(U2b, Ut2b, 256);
  k_cvtx<<<8192, 256, 0, stream>>>(x, xb);

  dim3 zgrid(512, 8, 2);
  k_zx<128><<<zgrid, 256, 0, stream>>>(xb, Wt1f, Wt1b, b1f, b1b, zxf, zxb);
  k_rec6<1><<<8, 1024, 0, stream>>>(zxf, zxb, Ut1f, Ut1b, h1, nullptr);
  k_ln<<<65536 / 4, 256, 0, stream>>>(h1, gamma, beta, ln1);
  k_zx<512><<<zgrid, 256, 0, stream>>>(ln1, Wt2f, Wt2b, b2f, b2b, zxf, zxb);
  k_rec6<2><<<8, 1024, 0, stream>>>(zxf, zxb, Ut2f, Ut2b, nullptr, (float*)d_out);
}

// Round 11
// 6167.046 us; speedup vs baseline: 2.9205x; 2.8681x over previous
//
#include <hip/hip_runtime.h>

// BiLSTM(128->2x256) -> LayerNorm(512) -> BiLSTM(512->2x256), B=64 T=1024.
// f16 MFMA inputs, f32 accum/cell. Recurrence: 16 persistent WGs x 512 thr
// = (2 u-half x 2 dir x 4 batch-group). Each WG holds HALF of U(dir) in
// registers (128 B-regs/wave, proven spill-free); own-half h via LDS double
// buffer; partner half via sentinel-polled exchange. NEW vs round 6: partner
// pairs are bid^8 (same XCD under round-robin dispatch); each WG reads
// HW_REG_XCC_ID and, when the partner is on the SAME XCD, polls with
// sc0-only loads served by the shared L2 (~250cy RT) instead of L3 (~700cy).
// Publishes are always sc0+sc1 (update L2 en route to L3) so any mix of load
// paths is correct; sticky fallback to L3 loads after 64 failed polls.

typedef __attribute__((ext_vector_type(8))) _Float16 half8;    // f16x8 MFMA frag
typedef __attribute__((ext_vector_type(4))) float f32x4;       // MFMA acc
typedef __attribute__((ext_vector_type(4))) unsigned short ushort4v;
typedef __attribute__((ext_vector_type(4))) unsigned int uint4v;

#define LOG2E 1.4426950408889634f
#define SENTW 0xFFFFFFFFu

static __device__ __forceinline__ unsigned short f2h(float f) {
  _Float16 h = (_Float16)f;
  return __builtin_bit_cast(unsigned short, h);
}
static __device__ __forceinline__ float h2f(unsigned short u) {
  _Float16 h = __builtin_bit_cast(_Float16, u);
  return (float)h;
}
static __device__ __forceinline__ float sigf(float x) {
  return __builtin_amdgcn_rcpf(1.f + __builtin_amdgcn_exp2f(-LOG2E * x));
}
static __device__ __forceinline__ float tanhf_(float x) {
  return 1.f - 2.f * __builtin_amdgcn_rcpf(__builtin_amdgcn_exp2f((2.f * LOG2E) * x) + 1.f);
}

// Exchange loads: slowv -> L3 (sc0 sc1); fast -> shared-L2 (sc0, bypass L1).
static __device__ __forceinline__ uint4v ld_b128_x(const uint4v* p, int slowv) {
  uint4v v;
  if (slowv) asm volatile("global_load_dwordx4 %0, %1, off sc0 sc1" : "=v"(v) : "v"(p));
  else       asm volatile("global_load_dwordx4 %0, %1, off sc0"     : "=v"(v) : "v"(p));
  return v;
}
// Publishes: always device-coherent (write-through L2 -> L3).
static __device__ __forceinline__ void st_b32_dev(unsigned* p, unsigned v) {
  asm volatile("global_store_dword %0, %1, off sc0 sc1" :: "v"(p), "v"(v) : "memory");
}
static __device__ __forceinline__ bool nosent(const uint4v& v) {
  return v.x != SENTW && v.y != SENTW && v.z != SENTW && v.w != SENTW;
}

// fill n16 16-byte chunks with the sentinel pattern
__global__ void k_fill(uint4v* p, unsigned n16) {
  const uint4v v = (uint4v){SENTW, SENTW, SENTW, SENTW};
  for (unsigned i = blockIdx.x * 256 + threadIdx.x; i < n16; i += gridDim.x * 256)
    p[i] = v;
}

// out[c][k] = f16(in[k][c]); in is [K][1024] f32, out is [1024][K] f16.
__global__ void k_transpose(const float* __restrict__ in, unsigned short* __restrict__ out, int K) {
  int idx = blockIdx.x * 256 + threadIdx.x;
  int c = idx / K, k = idx - c * K;
  out[idx] = f2h(in[k * 1024 + c]);
}

// x [b][t][128] f32 -> xb [(t*64+b)][128] f16
__global__ void k_cvtx(const float* __restrict__ x, unsigned short* __restrict__ xb) {
  int i = blockIdx.x * 256 + threadIdx.x;
  int o = i * 4;
  int k = o & 127, row = o >> 7;
  int b = row & 63, t = row >> 6;
  const f32x4 v = *(const f32x4*)(x + (size_t)((b << 10) + t) * 128 + k);
  ushort4v r;
  r.x = f2h(v.x); r.y = f2h(v.y); r.z = f2h(v.z); r.w = f2h(v.w);
  *(ushort4v*)(xb + o) = r;
}

// zx GEMM: A [65536 rows=(t*64+b)][K] f16 times Wt [1024][K] f16 (+bias)
// -> out [1024 t][1024 col][64 b] f16.  128x128 tiles, direct-global frags.
template<int K>
__global__ __launch_bounds__(256, 2) void k_zx(
    const unsigned short* __restrict__ A,
    const unsigned short* __restrict__ Wt_f, const unsigned short* __restrict__ Wt_b,
    const float* __restrict__ bias_f, const float* __restrict__ bias_b,
    unsigned short* __restrict__ out_f, unsigned short* __restrict__ out_b) {
  const int tid = threadIdx.x, w = tid >> 6, l = tid & 63;
  const int l16 = l & 15, lg = l >> 4;
  const int wm = w & 1, wn = w >> 1;
  const int rowbase = blockIdx.x * 128 + wm * 64;
  const int colbase = blockIdx.y * 128 + wn * 64;
  const unsigned short* Wt = blockIdx.z ? Wt_b : Wt_f;
  const float* bias = blockIdx.z ? bias_b : bias_f;
  unsigned short* out = blockIdx.z ? out_b : out_f;

  f32x4 acc[4][4];
#pragma unroll
  for (int nt = 0; nt < 4; nt++) {
    float bv = bias[colbase + nt * 16 + l16];
#pragma unroll
    for (int mt = 0; mt < 4; mt++) acc[mt][nt] = (f32x4){bv, bv, bv, bv};
  }

  for (int kf = 0; kf < K / 32; kf++) {
    const int ko = kf * 32 + lg * 8;
    half8 a[4], b[4];
#pragma unroll
    for (int mt = 0; mt < 4; mt++)
      a[mt] = *(const half8*)(A + (size_t)(rowbase + mt * 16 + l16) * K + ko);
#pragma unroll
    for (int nt = 0; nt < 4; nt++)
      b[nt] = *(const half8*)(Wt + (size_t)(colbase + nt * 16 + l16) * K + ko);
#pragma unroll
    for (int mt = 0; mt < 4; mt++)
#pragma unroll
      for (int nt = 0; nt < 4; nt++)
        acc[mt][nt] = __builtin_amdgcn_mfma_f32_16x16x32_f16(a[mt], b[nt], acc[mt][nt], 0, 0, 0);
  }

#pragma unroll
  for (int mt = 0; mt < 4; mt++) {
    const int rowchunk = rowbase + mt * 16;
    const int t = rowchunk >> 6;
    const int b0 = (rowchunk & 63) + lg * 4;
#pragma unroll
    for (int nt = 0; nt < 4; nt++) {
      const int c = colbase + nt * 16 + l16;
      ushort4v r;
      r.x = f2h(acc[mt][nt].x); r.y = f2h(acc[mt][nt].y);
      r.z = f2h(acc[mt][nt].z); r.w = f2h(acc[mt][nt].w);
      *(ushort4v*)(out + (((size_t)t << 10 | c) << 6) + b0) = r;
    }
  }
}

// Persistent recurrence. 16 WGs x 512 thr: bid = half*8 + d*4 + g.
// Partner = bid ^ 8 (other u-half, same XCD under round-robin dispatch).
// Exchange: L1 exch = h1 [(tt*64+b)][512] (doubles as LN input);
//           L2 exch = hist [t][d][g][half][16 b][128 u].
template<int LAYER>
__global__ __launch_bounds__(512, 2) void k_rec7(
    const unsigned short* __restrict__ zx_f, const unsigned short* __restrict__ zx_b,
    const unsigned short* __restrict__ Ut_f, const unsigned short* __restrict__ Ut_b,
    unsigned short* __restrict__ exch,
    int* __restrict__ xcc,               // [16] XCD ids, sentinel-filled
    float* __restrict__ out) {           // LAYER==2: [b][t][512] f32
  const int tid = threadIdx.x, wv = tid >> 6, l = tid & 63;
  const int l16 = l & 15, lg = l >> 4;
  const int bid = blockIdx.x;
  const int half = bid >> 3, d = (bid >> 2) & 1, g = bid & 3;
  const int b0 = g * 16;
  const int ug = half * 128 + wv * 16 + l16;   // this lane's u in [0,256)

  const unsigned short* zx = d ? zx_b : zx_f;
  const unsigned short* Ut = d ? Ut_b : Ut_f;

  // own-half h double-buffer in LDS: [slot][16 b][128 u], XOR-swizzled rows
  __shared__ unsigned short hlds[2 * 16 * 128];

  // ---- XCD discovery: pick L2 vs L3 exchange-load path ----
  unsigned my_xcc = __builtin_amdgcn_s_getreg((3 << 11) | 20) & 0xFu;  // HW_REG_XCC_ID[3:0]
  if (tid == 0) st_b32_dev((unsigned*)&xcc[bid], my_xcc);
  unsigned px = SENTW;
  {
    int gu = 0;
    while (true) {
      asm volatile("global_load_dword %0, %1, off sc0 sc1" : "=v"(px) : "v"(&xcc[bid ^ 8]));
      asm volatile("s_waitcnt vmcnt(0)" ::: "memory");
      if (px != SENTW || ++gu > (1 << 20)) break;
      __builtin_amdgcn_s_sleep(1);
    }
  }
  int slowv = (px == my_xcc && my_xcc < 8u) ? 0 : 1;   // 0 = same-XCD L2 path

  // B[q][j]: j 0..3 = OWN kf (half*4+j), j 4..7 = REMOTE kf ((half^1)*4+j-4)
  half8 B[4][8];
#pragma unroll
  for (int j = 0; j < 8; j++) {
    const int kf = (j < 4) ? (half * 4 + j) : ((half ^ 1) * 4 + (j - 4));
#pragma unroll
    for (int q = 0; q < 4; q++)
      B[q][j] = *(const half8*)(Ut + (size_t)(q * 256 + ug) * 256 + kf * 32 + lg * 8);
  }

  f32x4 c = (f32x4){0, 0, 0, 0};

  ushort4v zq[4];
  {
    const int t0 = d ? 1023 : 0;
#pragma unroll
    for (int q = 0; q < 4; q++)
      zq[q] = *(const ushort4v*)(zx + (((size_t)t0 << 10 | (q * 256 + ug)) << 6) + b0 + lg * 4);
  }

  for (int t = 0; t < 1024; t++) {
    const int tt = d ? 1023 - t : t;
    f32x4 acc[4];
#pragma unroll
    for (int q = 0; q < 4; q++)
      acc[q] = (f32x4){h2f(zq[q].x), h2f(zq[q].y), h2f(zq[q].z), h2f(zq[q].w)};

    if (t > 0) {
      // partner-half poll address (row = batch l16, 4x16B chunks by kfo,lg)
      const uint4v* rowp;
      if constexpr (LAYER == 1) {
        const int tp = d ? tt + 1 : tt - 1;   // time index of step t-1
        rowp = (const uint4v*)(exch + ((size_t)tp * 64 + b0 + l16) * 512 + d * 256 + (half ^ 1) * 128);
      } else {
        rowp = (const uint4v*)(exch + (((((size_t)(t - 1) * 2 + d) * 4 + g) * 2 + (half ^ 1)) * 2048)
                               + (size_t)l16 * 128);
      }
      uint4v pv0 = ld_b128_x(rowp + 0 + lg, slowv);
      uint4v pv1 = ld_b128_x(rowp + 4 + lg, slowv);
      uint4v pv2 = ld_b128_x(rowp + 8 + lg, slowv);
      uint4v pv3 = ld_b128_x(rowp + 12 + lg, slowv);

      // own-half h(t-1) from LDS (lgkmcnt path, overlaps the exchange RT)
      half8 ha[4];
#pragma unroll
      for (int kfo = 0; kfo < 4; kfo++) {
        const int idx = ((l16 * 128 + kfo * 32 + lg * 8) ^ ((l16 & 7) << 3)) + ((t - 1) & 1) * 2048;
        ha[kfo] = *(const half8*)&hlds[idx];
      }
#pragma unroll
      for (int kfo = 0; kfo < 4; kfo++)
#pragma unroll
        for (int q = 0; q < 4; q++)
          acc[q] = __builtin_amdgcn_mfma_f32_16x16x32_f16(ha[kfo], B[q][kfo], acc[q], 0, 0, 0);

      // sentinel poll on the partner data (only these 4 loads are in vmcnt)
      int tries = 0;
      while (true) {
        asm volatile("s_waitcnt vmcnt(0)" ::: "memory");
        __builtin_amdgcn_sched_barrier(0);
        bool ok = nosent(pv0) && nosent(pv1) && nosent(pv2) && nosent(pv3);
        if (__all(ok)) break;
        if (++tries > (1 << 16)) break;       // anti-hang bail
        if (tries == 64) slowv = 1;           // sticky fallback to L3 loads
        __builtin_amdgcn_s_sleep(1);
        pv0 = ld_b128_x(rowp + 0 + lg, slowv);
        pv1 = ld_b128_x(rowp + 4 + lg, slowv);
        pv2 = ld_b128_x(rowp + 8 + lg, slowv);
        pv3 = ld_b128_x(rowp + 12 + lg, slowv);
      }
      __builtin_amdgcn_sched_barrier(0);   // rule #18: no MFMA hoist above wait

      half8 pa0 = __builtin_bit_cast(half8, pv0);
      half8 pa1 = __builtin_bit_cast(half8, pv1);
      half8 pa2 = __builtin_bit_cast(half8, pv2);
      half8 pa3 = __builtin_bit_cast(half8, pv3);
#pragma unroll
      for (int q = 0; q < 4; q++) acc[q] = __builtin_amdgcn_mfma_f32_16x16x32_f16(pa0, B[q][4], acc[q], 0, 0, 0);
#pragma unroll
      for (int q = 0; q < 4; q++) acc[q] = __builtin_amdgcn_mfma_f32_16x16x32_f16(pa1, B[q][5], acc[q], 0, 0, 0);
#pragma unroll
      for (int q = 0; q < 4; q++) acc[q] = __builtin_amdgcn_mfma_f32_16x16x32_f16(pa2, B[q][6], acc[q], 0, 0, 0);
#pragma unroll
      for (int q = 0; q < 4; q++) acc[q] = __builtin_amdgcn_mfma_f32_16x16x32_f16(pa3, B[q][7], acc[q], 0, 0, 0);
    }

    if (t + 1 < 1024) {   // zx prefetch AFTER the poll (kept out of poll vmcnt)
      const int tn = d ? tt - 1 : tt + 1;
#pragma unroll
      for (int q = 0; q < 4; q++)
        zq[q] = *(const ushort4v*)(zx + (((size_t)tn << 10 | (q * 256 + ug)) << 6) + b0 + lg * 4);
    }

    // gates + state update; D-frag: row(b_local) = lg*4+rr, col(u) = l16
    unsigned short hb16[4];
    float hf[4];
#pragma unroll
    for (int rr = 0; rr < 4; rr++) {
      const float zi = acc[0][rr], zf = acc[1][rr], zg = acc[2][rr], zo = acc[3][rr];
      const float cc = sigf(zf) * c[rr] + sigf(zi) * tanhf_(zg);
      c[rr] = cc;
      hf[rr] = sigf(zo) * tanhf_(cc);
      hb16[rr] = f2h(hf[rr]);
    }

    // publish partner-visible h FIRST (pack lane-pairs into 4B device stores)
    {
      unsigned prt[4];
#pragma unroll
      for (int rr = 0; rr < 4; rr++)
        prt[rr] = (unsigned)__shfl_xor((int)(unsigned)hb16[rr], 1);
      const int odd = l16 & 1;
      const int rb = odd ? 2 : 0;
#pragma unroll
      for (int k = 0; k < 2; k++) {
        const int rr = rb + k;
        const int bl = lg * 4 + rr;
        const unsigned lo = odd ? prt[rr] : (unsigned)hb16[rr];
        const unsigned hi = odd ? (unsigned)hb16[rr] : prt[rr];
        const unsigned pk = (lo & 0xffffu) | (hi << 16);
        if constexpr (LAYER == 1) {
          const size_t widx = (((size_t)tt * 64 + b0 + bl) * 512 + d * 256 + (ug & ~1)) >> 1;
          st_b32_dev((unsigned*)exch + widx, pk);
        } else {
          const size_t base = ((((size_t)t * 2 + d) * 4 + g) * 2 + half) * 2048;
          const size_t widx = (base + (size_t)bl * 128 + ((ug & ~1) - half * 128)) >> 1;
          st_b32_dev((unsigned*)exch + widx, pk);
        }
      }
    }

    if constexpr (LAYER == 2) {
#pragma unroll
      for (int rr = 0; rr < 4; rr++) {
        const int b = b0 + lg * 4 + rr;
        out[((size_t)b << 10 | tt) * 512 + d * 256 + ug] = hf[rr];
      }
    }

    // own-half h(t) -> LDS (slot t&1; read next step from this slot)
#pragma unroll
    for (int rr = 0; rr < 4; rr++) {
      const int bl = lg * 4 + rr;
      const int ul = wv * 16 + l16;
      const int idx = ((bl * 128 + ul) ^ ((bl & 7) << 3)) + (t & 1) * 2048;
      hlds[idx] = hb16[rr];
    }

    // raw barrier: only LDS ordering (no vmcnt drain -> publishes fly on)
    asm volatile("s_waitcnt lgkmcnt(0)" ::: "memory");
    __builtin_amdgcn_s_barrier();
  }
}

// LayerNorm over 512 features; one wave per row. f16 in/out, f32 math.
__global__ __launch_bounds__(256) void k_ln(
    const unsigned short* __restrict__ h1, const float* __restrict__ gamma,
    const float* __restrict__ beta, unsigned short* __restrict__ ln1) {
  const int tid = threadIdx.x, w = tid >> 6, l = tid & 63;
  const size_t row = (size_t)blockIdx.x * 4 + w;
  const unsigned short* src = h1 + row * 512 + l * 8;
  const ushort4v v0 = *(const ushort4v*)src;
  const ushort4v v1 = *(const ushort4v*)(src + 4);
  float xv[8] = {h2f(v0.x), h2f(v0.y), h2f(v0.z), h2f(v0.w),
                 h2f(v1.x), h2f(v1.y), h2f(v1.z), h2f(v1.w)};
  float sum = 0.f, ssq = 0.f;
#pragma unroll
  for (int i = 0; i < 8; i++) { sum += xv[i]; ssq += xv[i] * xv[i]; }
#pragma unroll
  for (int off = 32; off; off >>= 1) {
    sum += __shfl_xor(sum, off);
    ssq += __shfl_xor(ssq, off);
  }
  const float mu = sum * (1.f / 512.f);
  const float var = ssq * (1.f / 512.f) - mu * mu;
  const float rs = __builtin_amdgcn_rsqf(var + 1e-3f);
  const f32x4 g0 = *(const f32x4*)(gamma + l * 8);
  const f32x4 g1 = *(const f32x4*)(gamma + l * 8 + 4);
  const f32x4 e0 = *(const f32x4*)(beta + l * 8);
  const f32x4 e1 = *(const f32x4*)(beta + l * 8 + 4);
  float gg[8] = {g0.x, g0.y, g0.z, g0.w, g1.x, g1.y, g1.z, g1.w};
  float ee[8] = {e0.x, e0.y, e0.z, e0.w, e1.x, e1.y, e1.z, e1.w};
  unsigned short hh[8];
#pragma unroll
  for (int i = 0; i < 8; i++)
    hh[i] = f2h((xv[i] - mu) * rs * gg[i] + ee[i]);
  unsigned short* dst = ln1 + row * 512 + l * 8;
  *(ushort4v*)dst = (ushort4v){hh[0], hh[1], hh[2], hh[3]};
  *(ushort4v*)(dst + 4) = (ushort4v){hh[4], hh[5], hh[6], hh[7]};
}

extern "C" void kernel_launch(void* const* d_in, const int* in_sizes, int n_in,
                              void* d_out, int out_size, void* d_ws, size_t ws_size,
                              hipStream_t stream) {
  (void)in_sizes; (void)n_in; (void)out_size; (void)ws_size;
  const float* x     = (const float*)d_in[0];
  const float* W1f   = (const float*)d_in[1];
  const float* U1f   = (const float*)d_in[2];
  const float* b1f   = (const float*)d_in[3];
  const float* W1b   = (const float*)d_in[4];
  const float* U1b   = (const float*)d_in[5];
  const float* b1b   = (const float*)d_in[6];
  const float* gamma = (const float*)d_in[7];
  const float* beta  = (const float*)d_in[8];
  const float* W2f   = (const float*)d_in[9];
  const float* U2f   = (const float*)d_in[10];
  const float* b2f   = (const float*)d_in[11];
  const float* W2b   = (const float*)d_in[12];
  const float* U2b   = (const float*)d_in[13];
  const float* b2b   = (const float*)d_in[14];

  char* ws = (char*)d_ws;
  size_t ofs = 0;
  auto alloc = [&](size_t bytes) -> void* {
    void* p = ws + ofs;
    ofs += (bytes + 255) & ~(size_t)255;
    return p;
  };
  int* xcc1             = (int*)alloc(256);     // 16 ints, sentinel-filled
  int* xcc2             = (int*)alloc(256);
  unsigned short* Wt1f  = (unsigned short*)alloc((size_t)1024*128*2);
  unsigned short* Wt1b  = (unsigned short*)alloc((size_t)1024*128*2);
  unsigned short* Ut1f  = (unsigned short*)alloc((size_t)1024*256*2);
  unsigned short* Ut1b  = (unsigned short*)alloc((size_t)1024*256*2);
  unsigned short* Ut2f  = (unsigned short*)alloc((size_t)1024*256*2);
  unsigned short* Ut2b  = (unsigned short*)alloc((size_t)1024*256*2);
  unsigned short* Wt2f  = (unsigned short*)alloc((size_t)1024*512*2);
  unsigned short* Wt2b  = (unsigned short*)alloc((size_t)1024*512*2);
  unsigned short* zxf   = (unsigned short*)alloc((size_t)1024*1024*64*2);  // 128MB
  unsigned short* zxb   = (unsigned short*)alloc((size_t)1024*1024*64*2);  // 128MB
  const size_t HH2_BYTES = (size_t)1024*2*4*2*16*128*2;                    // 64MB
  unsigned short* hist  = (unsigned short*)alloc(HH2_BYTES);               // ws >= 323MB proven

  // d_out (128MB): xb [0,16MB) dead after zx1 -> h1 [0,64MB) sentinel-filled,
  // exchange+output of k_rec7<1>, dead after LN -> ln1 [64,128MB) dead after
  // zx2 -> final f32 out overwrites all 128MB in k_rec7<2>.
  unsigned short* xb  = (unsigned short*)d_out;
  unsigned short* h1  = (unsigned short*)d_out;
  unsigned short* ln1 = (unsigned short*)d_out + (size_t)65536 * 512;

  k_fill<<<1, 256, 0, stream>>>((uint4v*)xcc1, 32);   // both xcc arrays (512B)
  k_transpose<<<1024 * 128 / 256, 256, 0, stream>>>(W1f, Wt1f, 128);
  k_transpose<<<1024 * 128 / 256, 256, 0, stream>>>(W1b, Wt1b, 128);
  k_transpose<<<1024 * 256 / 256, 256, 0, stream>>>(U1f, Ut1f, 256);
  k_transpose<<<1024 * 256 / 256, 256, 0, stream>>>(U1b, Ut1b, 256);
  k_transpose<<<1024 * 512 / 256, 256, 0, stream>>>(W2f, Wt2f, 512);
  k_transpose<<<1024 * 512 / 256, 256, 0, stream>>>(W2b, Wt2b, 512);
  k_transpose<<<1024 * 256 / 256, 256, 0, stream>>>(U2f, Ut2f, 256);
  k_transpose<<<1024 * 256 / 256, 256, 0, stream>>>(U2b, Ut2b, 256);
  k_cvtx<<<8192, 256, 0, stream>>>(x, xb);

  dim3 zgrid(512, 8, 2);
  k_zx<128><<<zgrid, 256, 0, stream>>>(xb, Wt1f, Wt1b, b1f, b1b, zxf, zxb);
  k_fill<<<2048, 256, 0, stream>>>((uint4v*)h1, 65536u * 512u / 8u);
  k_rec7<1><<<16, 512, 0, stream>>>(zxf, zxb, Ut1f, Ut1b, h1, xcc1, nullptr);
  k_ln<<<65536 / 4, 256, 0, stream>>>(h1, gamma, beta, ln1);
  k_zx<512><<<zgrid, 256, 0, stream>>>(ln1, Wt2f, Wt2b, b2f, b2b, zxf, zxb);
  k_fill<<<2048, 256, 0, stream>>>((uint4v*)hist, (unsigned)(HH2_BYTES / 16));
  k_rec7<2><<<16, 512, 0, stream>>>(zxf, zxb, Ut2f, Ut2b, hist, xcc2, (float*)d_out);
}